// Round 1
// 1164.601 us; speedup vs baseline: 1.0378x; 1.0378x over previous
//
#include <hip/hip_runtime.h>
#include <cstdint>
#include <cstddef>

#define T_DIM 8192
#define H_DIM 1024
#define I_DIM 3584
#define E_DIM 8
#define BK 32

typedef __attribute__((ext_vector_type(4))) float f32x4;
typedef __attribute__((ext_vector_type(8))) __bf16 bf16x8;
typedef __attribute__((ext_vector_type(8))) unsigned short u16x8;
typedef __attribute__((ext_vector_type(4))) unsigned short u16x4;

// fp32 -> bf16 round-to-nearest-even (finite inputs)
static __device__ inline unsigned short f2b(float f) {
    unsigned int u = __builtin_bit_cast(unsigned int, f);
    u += 0x7FFFu + ((u >> 16) & 1u);
    return (unsigned short)(u >> 16);
}

static __device__ inline bf16x8 ldfrag(const unsigned short* p) {
    return __builtin_bit_cast(bf16x8, *(const u16x8*)p);
}

// async global->LDS, 16B per lane. LDS dest is wave-uniform base + lane*16 (HW rule).
static __device__ inline void glds16(const unsigned short* g, unsigned short* l) {
    __builtin_amdgcn_global_load_lds(
        (const __attribute__((address_space(1))) void*)g,
        (__attribute__((address_space(3))) void*)l,
        16, 0, 0);
}

#define CONV_BLOCKS 14336   // NW / (256*8)

// ---------------- prep: 3x weight fp32->bf16 converts + router, one dispatch ----
__global__ __launch_bounds__(256) void prep_kernel(
    const float* __restrict__ w1, const float* __restrict__ w3,
    const float* __restrict__ w2,
    unsigned short* __restrict__ w1b, unsigned short* __restrict__ w3b,
    unsigned short* __restrict__ w2b,
    const float* __restrict__ x, const float* __restrict__ gw,
    const float* __restrict__ gb, int* __restrict__ counts,
    int* __restrict__ tok_exp, float* __restrict__ tok_w)
{
    const int b = blockIdx.x;
    if (b < 3 * CONV_BLOCKS) {
        const float* src; unsigned short* dst;
        int part = b / CONV_BLOCKS;
        if (part == 0)      { src = w1; dst = w1b; }
        else if (part == 1) { src = w3; dst = w3b; }
        else                { src = w2; dst = w2b; }
        long i = ((long)(b - part * CONV_BLOCKS) * 256 + threadIdx.x) * 8;
        f32x4 f0 = *(const f32x4*)(src + i);
        f32x4 f1 = *(const f32x4*)(src + i + 4);
        u16x8 o;
        o[0] = f2b(f0[0]); o[1] = f2b(f0[1]); o[2] = f2b(f0[2]); o[3] = f2b(f0[3]);
        o[4] = f2b(f1[0]); o[5] = f2b(f1[1]); o[6] = f2b(f1[2]); o[7] = f2b(f1[3]);
        *(u16x8*)(dst + i) = o;
        return;
    }
    // router: 4 tokens per block (1 wave each)
    const int t = (b - 3 * CONV_BLOCKS) * 4 + (threadIdx.x >> 6);
    const int lane = threadIdx.x & 63;
    const float* xp = x + (size_t)t * H_DIM;
    float xr[16];
#pragma unroll
    for (int i = 0; i < 16; i++) xr[i] = xp[lane + 64 * i];
    float lg[E_DIM];
#pragma unroll
    for (int e = 0; e < E_DIM; e++) {
        const float* gp = gw + e * H_DIM;
        float s = 0.f;
#pragma unroll
        for (int i = 0; i < 16; i++) s += xr[i] * gp[lane + 64 * i];
        for (int off = 32; off; off >>= 1) s += __shfl_xor(s, off, 64);
        lg[e] = s + gb[e];
    }
    if (lane == 0) {
        float mx = lg[0];
#pragma unroll
        for (int e = 1; e < E_DIM; e++) mx = fmaxf(mx, lg[e]);
        float p[E_DIM], sum = 0.f;
#pragma unroll
        for (int e = 0; e < E_DIM; e++) { p[e] = __expf(lg[e] - mx); sum += p[e]; }
        float inv = 1.0f / sum;
        int e0 = 0; float p0 = p[0];
#pragma unroll
        for (int e = 1; e < E_DIM; e++) if (p[e] > p0) { p0 = p[e]; e0 = e; }
        int e1 = -1; float p1 = -1.0f;
#pragma unroll
        for (int e = 0; e < E_DIM; e++) if (e != e0 && p[e] > p1) { p1 = p[e]; e1 = e; }
        tok_exp[t * 2]     = e0;
        tok_exp[t * 2 + 1] = e1;
        tok_w[t * 2]     = p0 * inv;
        tok_w[t * 2 + 1] = p1 * inv;
        atomicAdd(&counts[e0], 1);
        atomicAdd(&counts[e1], 1);
    }
}

// ---------------- exclusive scan over 8 counts ----------------
__global__ void scan_kernel(const int* __restrict__ counts,
                            int* __restrict__ offs, int* __restrict__ wptr)
{
    if (threadIdx.x == 0 && blockIdx.x == 0) {
        int acc = 0;
        for (int e = 0; e < E_DIM; e++) { offs[e] = acc; wptr[e] = acc; acc += counts[e]; }
        offs[E_DIM] = acc;
    }
}

// ---------------- gather: bf16 rows + token->row map ----------------
__global__ __launch_bounds__(256) void gather_kernel(
    const float* __restrict__ x, const int* __restrict__ tok_exp,
    int* __restrict__ wptr, int* __restrict__ tok_row,
    unsigned short* __restrict__ Xg)
{
    const int t = blockIdx.x;
    __shared__ int rows[2];
    if (threadIdx.x < 2) {
        int e = tok_exp[t * 2 + threadIdx.x];
        int r = atomicAdd(&wptr[e], 1);
        rows[threadIdx.x] = r;
        tok_row[t * 2 + threadIdx.x] = r;
    }
    __syncthreads();
    const int c = threadIdx.x * 4;
    f32x4 v = *(const f32x4*)(x + (size_t)t * H_DIM + c);
    u16x4 b;
    b[0] = f2b(v[0]); b[1] = f2b(v[1]); b[2] = f2b(v[2]); b[3] = f2b(v[3]);
    *(u16x4*)&Xg[(size_t)rows[0] * H_DIM + c] = b;
    *(u16x4*)&Xg[(size_t)rows[1] * H_DIM + c] = b;
}

// ---------------- GEMM1: Hg = silu(Xg @ w1^T) * (Xg @ w3^T) ----------------
// 2-phase double-buffered K-loop: STAGE(next) issued before COMPUTE(cur),
// ONE barrier per K-step (T3 minimum-2-phase recipe).
__global__ __launch_bounds__(256) void gemm13_kernel(
    const unsigned short* __restrict__ Xg, const unsigned short* __restrict__ w1b,
    const unsigned short* __restrict__ w3b, const int* __restrict__ offs,
    unsigned short* __restrict__ Hg)
{
    const int e = blockIdx.z;
    const int base = offs[e];
    const int Me = offs[e + 1] - base;
    const int m0 = blockIdx.y * 128;
    if (m0 >= Me) return;
    const int n0 = blockIdx.x * 64;
    const int tid = threadIdx.x;
    const int lane = tid & 63;
    const int wv = tid >> 6;

    __shared__ __align__(16) unsigned short As[2][128 * BK];
    __shared__ __align__(16) unsigned short B1s[2][64 * BK];
    __shared__ __align__(16) unsigned short B3s[2][64 * BK];

    const int wm = wv & 1;
    const int wn = wv >> 1;
    const int frow = lane & 15;
    const int koff = (lane >> 4) * 8;

    f32x4 acc1[4][2], acc3[4][2];
#pragma unroll
    for (int i = 0; i < 4; i++)
#pragma unroll
        for (int j = 0; j < 2; j++) {
            acc1[i][j] = f32x4{0.f, 0.f, 0.f, 0.f};
            acc3[i][j] = f32x4{0.f, 0.f, 0.f, 0.f};
        }

    const int lrow = lane >> 2;
    const int lcol = (lane & 3) * 8;
    const unsigned short* Ag0 = Xg + (size_t)(base + m0 + wv * 32 + lrow) * H_DIM + lcol;
    const unsigned short* Ag1 = Ag0 + 16 * H_DIM;
    const size_t wb = (size_t)e * I_DIM * H_DIM + (size_t)(n0 + wv * 16 + lrow) * H_DIM + lcol;
    const unsigned short* B1g = w1b + wb;
    const unsigned short* B3g = w3b + wb;
    const int aoff0 = (wv * 2) * 16 * BK;
    const int aoff1 = (wv * 2 + 1) * 16 * BK;
    const int boff  = wv * 16 * BK;

    auto stage = [&](int buf, int kk) {
        glds16(Ag0 + kk, &As[buf][aoff0]);
        glds16(Ag1 + kk, &As[buf][aoff1]);
        glds16(B1g + kk, &B1s[buf][boff]);
        glds16(B3g + kk, &B3s[buf][boff]);
    };
    auto comp = [&](const unsigned short* Asb, const unsigned short* B1b,
                    const unsigned short* B3b) {
        bf16x8 a[4], b1[2], b3[2];
#pragma unroll
        for (int im = 0; im < 4; im++)
            a[im] = ldfrag(&Asb[(wm * 64 + im * 16 + frow) * BK + koff]);
#pragma unroll
        for (int jn = 0; jn < 2; jn++) {
            b1[jn] = ldfrag(&B1b[(wn * 32 + jn * 16 + frow) * BK + koff]);
            b3[jn] = ldfrag(&B3b[(wn * 32 + jn * 16 + frow) * BK + koff]);
        }
#pragma unroll
        for (int im = 0; im < 4; im++)
#pragma unroll
            for (int jn = 0; jn < 2; jn++) {
                acc1[im][jn] = __builtin_amdgcn_mfma_f32_16x16x32_bf16(a[im], b1[jn], acc1[im][jn], 0, 0, 0);
                acc3[im][jn] = __builtin_amdgcn_mfma_f32_16x16x32_bf16(a[im], b3[jn], acc3[im][jn], 0, 0, 0);
            }
    };

    stage(0, 0);
    // H_DIM/BK = 32 (even): unroll by 2 for static buffer indices
    for (int kk = 0; kk < H_DIM; kk += 2 * BK) {
        __syncthreads();                     // buf0(kk) ready; prev reads of buf1 done
        stage(1, kk + BK);                   // kk+BK < H_DIM always
        comp(As[0], B1s[0], B3s[0]);
        __syncthreads();                     // buf1 ready; reads of buf0 done
        if (kk + 2 * BK < H_DIM) stage(0, kk + 2 * BK);
        comp(As[1], B1s[1], B3s[1]);
    }

    // epilogue: SwiGLU, bf16 store (C layout: col=lane&15, row=(lane>>4)*4+r)
#pragma unroll
    for (int im = 0; im < 4; im++) {
        const int rb = m0 + wm * 64 + im * 16 + (lane >> 4) * 4;
#pragma unroll
        for (int jn = 0; jn < 2; jn++) {
            const int cb = n0 + wn * 32 + jn * 16 + frow;
            f32x4 v1 = acc1[im][jn], v3 = acc3[im][jn];
#pragma unroll
            for (int r = 0; r < 4; r++) {
                const int row = rb + r;
                if (row < Me) {
                    float xx = v1[r];
                    float h = (xx / (1.0f + __expf(-xx))) * v3[r];
                    Hg[(size_t)(base + row) * I_DIM + cb] = f2b(h);
                }
            }
        }
    }
}

// ---------------- GEMM2: Og[row] = Hg[row] @ w2[e]^T (plain stores, no atomics) --
__global__ __launch_bounds__(256) void gemm2_kernel(
    const unsigned short* __restrict__ Hg, const unsigned short* __restrict__ w2b,
    const int* __restrict__ offs, float* __restrict__ Og)
{
    const int e = blockIdx.z;
    const int base = offs[e];
    const int Me = offs[e + 1] - base;
    const int m0 = blockIdx.y * 128;
    if (m0 >= Me) return;
    const int n0 = blockIdx.x * 128;
    const int tid = threadIdx.x;
    const int lane = tid & 63;
    const int wv = tid >> 6;

    __shared__ __align__(16) unsigned short As[2][128 * BK];
    __shared__ __align__(16) unsigned short Bs[2][128 * BK];

    const int wm = wv & 1;
    const int wn = wv >> 1;
    const int frow = lane & 15;
    const int koff = (lane >> 4) * 8;

    f32x4 acc[4][4];
#pragma unroll
    for (int i = 0; i < 4; i++)
#pragma unroll
        for (int j = 0; j < 4; j++) acc[i][j] = f32x4{0.f, 0.f, 0.f, 0.f};

    const int lrow = lane >> 2;
    const int lcol = (lane & 3) * 8;
    const unsigned short* Ag0 = Hg + (size_t)(base + m0 + wv * 32 + lrow) * I_DIM + lcol;
    const unsigned short* Ag1 = Ag0 + 16 * I_DIM;
    const size_t wbase = (size_t)e * H_DIM * I_DIM;
    const unsigned short* Bg0 = w2b + wbase + (size_t)(n0 + wv * 32 + lrow) * I_DIM + lcol;
    const unsigned short* Bg1 = Bg0 + 16 * I_DIM;
    const int aoff0 = (wv * 2) * 16 * BK;
    const int aoff1 = (wv * 2 + 1) * 16 * BK;

    auto stage = [&](int buf, int kk) {
        glds16(Ag0 + kk, &As[buf][aoff0]);
        glds16(Ag1 + kk, &As[buf][aoff1]);
        glds16(Bg0 + kk, &Bs[buf][aoff0]);
        glds16(Bg1 + kk, &Bs[buf][aoff1]);
    };
    auto comp = [&](const unsigned short* Asb, const unsigned short* Bsb) {
        bf16x8 a[4], b[4];
#pragma unroll
        for (int im = 0; im < 4; im++)
            a[im] = ldfrag(&Asb[(wm * 64 + im * 16 + frow) * BK + koff]);
#pragma unroll
        for (int jn = 0; jn < 4; jn++)
            b[jn] = ldfrag(&Bsb[(wn * 64 + jn * 16 + frow) * BK + koff]);
#pragma unroll
        for (int im = 0; im < 4; im++)
#pragma unroll
            for (int jn = 0; jn < 4; jn++)
                acc[im][jn] = __builtin_amdgcn_mfma_f32_16x16x32_bf16(a[im], b[jn], acc[im][jn], 0, 0, 0);
    };

    stage(0, 0);
    // I_DIM/BK = 112 (even): unroll by 2 for static buffer indices
    for (int kk = 0; kk < I_DIM; kk += 2 * BK) {
        __syncthreads();
        stage(1, kk + BK);                   // kk+BK < I_DIM always
        comp(As[0], Bs[0]);
        __syncthreads();
        if (kk + 2 * BK < I_DIM) stage(0, kk + 2 * BK);
        comp(As[1], Bs[1]);
    }

    // epilogue: dense per-row store into Og (combine happens in combine_kernel)
#pragma unroll
    for (int im = 0; im < 4; im++) {
        const int rb = m0 + wm * 64 + im * 16 + (lane >> 4) * 4;
#pragma unroll
        for (int jn = 0; jn < 4; jn++) {
            const int cb = n0 + wn * 64 + jn * 16 + frow;
            f32x4 v = acc[im][jn];
#pragma unroll
            for (int r = 0; r < 4; r++) {
                const int row = rb + r;
                if (row < Me)
                    Og[(size_t)(base + row) * H_DIM + cb] = v[r];
            }
        }
    }
}

// ---------------- combine: out[t] = w0*Og[r0] + w1*Og[r1] ----------------
__global__ __launch_bounds__(256) void combine_kernel(
    const float* __restrict__ Og, const int* __restrict__ tok_row,
    const float* __restrict__ tok_w, float* __restrict__ out)
{
    const int t = blockIdx.x;
    const int c = threadIdx.x * 4;
    const int r0 = tok_row[t * 2];
    const int r1 = tok_row[t * 2 + 1];
    const float w0 = tok_w[t * 2];
    const float w1 = tok_w[t * 2 + 1];
    f32x4 a = *(const f32x4*)(Og + (size_t)r0 * H_DIM + c);
    f32x4 b = *(const f32x4*)(Og + (size_t)r1 * H_DIM + c);
    f32x4 o;
#pragma unroll
    for (int i = 0; i < 4; i++) o[i] = a[i] * w0 + b[i] * w1;
    *(f32x4*)(out + (size_t)t * H_DIM + c) = o;
}

extern "C" void kernel_launch(void* const* d_in, const int* in_sizes, int n_in,
                              void* d_out, int out_size, void* d_ws, size_t ws_size,
                              hipStream_t stream) {
    const float* x  = (const float*)d_in[0];
    const float* gw = (const float*)d_in[1];
    const float* gb = (const float*)d_in[2];
    const float* w1 = (const float*)d_in[3];
    const float* w2 = (const float*)d_in[4];
    const float* w3 = (const float*)d_in[5];
    float* out = (float*)d_out;

    char* ws = (char*)d_ws;
    int* counts  = (int*)ws;                 // 8
    int* wptr    = counts + 8;               // 8
    int* offs    = wptr + 8;                 // 9
    int* tok_exp = (int*)(ws + 256);         // 2T
    int* tok_row = tok_exp + 2 * T_DIM;      // 2T
    float* tok_w = (float*)(tok_row + 2 * T_DIM); // 2T
    size_t ofs = 256 + (size_t)3 * 2 * T_DIM * 4;
    ofs = (ofs + 255) & ~(size_t)255;
    const size_t ROWS = 2 * T_DIM + 128;     // slack for 128-tile overshoot
    const long NW = (long)E_DIM * I_DIM * H_DIM;
    unsigned short* Xg  = (unsigned short*)(ws + ofs); ofs += ROWS * H_DIM * 2;
    unsigned short* Hg  = (unsigned short*)(ws + ofs); ofs += ROWS * I_DIM * 2;
    unsigned short* w2b = (unsigned short*)(ws + ofs); ofs += (size_t)NW * 2;
    unsigned short* w1b = (unsigned short*)(ws + ofs); ofs += (size_t)NW * 2;
    unsigned short* w3b = (unsigned short*)(ws + ofs); ofs += (size_t)NW * 2;
    // Og (ROWS*H fp32 = 67.6MB) aliases w1b+w3b (117.4MB) — dead after gemm13.
    float* Og = (float*)w1b;

    hipMemsetAsync(counts, 0, 64, stream);
    prep_kernel<<<3 * CONV_BLOCKS + T_DIM / 4, 256, 0, stream>>>(
        w1, w3, w2, w1b, w3b, w2b, x, gw, gb, counts, tok_exp, tok_w);
    scan_kernel<<<1, 64, 0, stream>>>(counts, offs, wptr);
    gather_kernel<<<T_DIM, 256, 0, stream>>>(x, tok_exp, wptr, tok_row, Xg);
    gemm13_kernel<<<dim3(I_DIM / 64, 64, E_DIM), 256, 0, stream>>>(Xg, w1b, w3b, offs, Hg);
    gemm2_kernel<<<dim3(H_DIM / 128, 64, E_DIM), 256, 0, stream>>>(Hg, w2b, offs, Og);
    combine_kernel<<<T_DIM, 256, 0, stream>>>(Og, tok_row, tok_w, out);
}

// Round 2
// 1163.915 us; speedup vs baseline: 1.0384x; 1.0006x over previous
//
#include <hip/hip_runtime.h>
#include <cstdint>
#include <cstddef>

#define T_DIM 8192
#define H_DIM 1024
#define I_DIM 3584
#define E_DIM 8
#define BK 32

typedef __attribute__((ext_vector_type(4))) float f32x4;
typedef __attribute__((ext_vector_type(8))) __bf16 bf16x8;
typedef __attribute__((ext_vector_type(8))) unsigned short u16x8;
typedef __attribute__((ext_vector_type(4))) unsigned short u16x4;

// fp32 -> bf16 round-to-nearest-even (finite inputs)
static __device__ inline unsigned short f2b(float f) {
    unsigned int u = __builtin_bit_cast(unsigned int, f);
    u += 0x7FFFu + ((u >> 16) & 1u);
    return (unsigned short)(u >> 16);
}

static __device__ inline bf16x8 ldfrag(const unsigned short* p) {
    return __builtin_bit_cast(bf16x8, *(const u16x8*)p);
}

// async global->LDS, 16B per lane. LDS dest is wave-uniform base + lane*16 (HW rule).
static __device__ inline void glds16(const unsigned short* g, unsigned short* l) {
    __builtin_amdgcn_global_load_lds(
        (const __attribute__((address_space(1))) void*)g,
        (__attribute__((address_space(3))) void*)l,
        16, 0, 0);
}

#define CONV_BLOCKS 14336   // NW / (256*8)

// ---------------- prep: 3x weight fp32->bf16 converts + router, one dispatch ----
__global__ __launch_bounds__(256) void prep_kernel(
    const float* __restrict__ w1, const float* __restrict__ w3,
    const float* __restrict__ w2,
    unsigned short* __restrict__ w1b, unsigned short* __restrict__ w3b,
    unsigned short* __restrict__ w2b,
    const float* __restrict__ x, const float* __restrict__ gw,
    const float* __restrict__ gb, int* __restrict__ counts,
    int* __restrict__ tok_exp, float* __restrict__ tok_w)
{
    const int b = blockIdx.x;
    if (b < 3 * CONV_BLOCKS) {
        const float* src; unsigned short* dst;
        int part = b / CONV_BLOCKS;
        if (part == 0)      { src = w1; dst = w1b; }
        else if (part == 1) { src = w3; dst = w3b; }
        else                { src = w2; dst = w2b; }
        long i = ((long)(b - part * CONV_BLOCKS) * 256 + threadIdx.x) * 8;
        f32x4 f0 = *(const f32x4*)(src + i);
        f32x4 f1 = *(const f32x4*)(src + i + 4);
        u16x8 o;
        o[0] = f2b(f0[0]); o[1] = f2b(f0[1]); o[2] = f2b(f0[2]); o[3] = f2b(f0[3]);
        o[4] = f2b(f1[0]); o[5] = f2b(f1[1]); o[6] = f2b(f1[2]); o[7] = f2b(f1[3]);
        *(u16x8*)(dst + i) = o;
        return;
    }
    // router: 4 tokens per block (1 wave each)
    const int t = (b - 3 * CONV_BLOCKS) * 4 + (threadIdx.x >> 6);
    const int lane = threadIdx.x & 63;
    const float* xp = x + (size_t)t * H_DIM;
    float xr[16];
#pragma unroll
    for (int i = 0; i < 16; i++) xr[i] = xp[lane + 64 * i];
    float lg[E_DIM];
#pragma unroll
    for (int e = 0; e < E_DIM; e++) {
        const float* gp = gw + e * H_DIM;
        float s = 0.f;
#pragma unroll
        for (int i = 0; i < 16; i++) s += xr[i] * gp[lane + 64 * i];
        for (int off = 32; off; off >>= 1) s += __shfl_xor(s, off, 64);
        lg[e] = s + gb[e];
    }
    if (lane == 0) {
        float mx = lg[0];
#pragma unroll
        for (int e = 1; e < E_DIM; e++) mx = fmaxf(mx, lg[e]);
        float p[E_DIM], sum = 0.f;
#pragma unroll
        for (int e = 0; e < E_DIM; e++) { p[e] = __expf(lg[e] - mx); sum += p[e]; }
        float inv = 1.0f / sum;
        int e0 = 0; float p0 = p[0];
#pragma unroll
        for (int e = 1; e < E_DIM; e++) if (p[e] > p0) { p0 = p[e]; e0 = e; }
        int e1 = -1; float p1 = -1.0f;
#pragma unroll
        for (int e = 0; e < E_DIM; e++) if (e != e0 && p[e] > p1) { p1 = p[e]; e1 = e; }
        tok_exp[t * 2]     = e0;
        tok_exp[t * 2 + 1] = e1;
        tok_w[t * 2]     = p0 * inv;
        tok_w[t * 2 + 1] = p1 * inv;
        atomicAdd(&counts[e0], 1);
        atomicAdd(&counts[e1], 1);
    }
}

// ---------------- exclusive scan over 8 counts ----------------
__global__ void scan_kernel(const int* __restrict__ counts,
                            int* __restrict__ offs, int* __restrict__ wptr)
{
    if (threadIdx.x == 0 && blockIdx.x == 0) {
        int acc = 0;
        for (int e = 0; e < E_DIM; e++) { offs[e] = acc; wptr[e] = acc; acc += counts[e]; }
        offs[E_DIM] = acc;
    }
}

// ---------------- gather: bf16 rows + token->row map ----------------
__global__ __launch_bounds__(256) void gather_kernel(
    const float* __restrict__ x, const int* __restrict__ tok_exp,
    int* __restrict__ wptr, int* __restrict__ tok_row,
    unsigned short* __restrict__ Xg)
{
    const int t = blockIdx.x;
    __shared__ int rows[2];
    if (threadIdx.x < 2) {
        int e = tok_exp[t * 2 + threadIdx.x];
        int r = atomicAdd(&wptr[e], 1);
        rows[threadIdx.x] = r;
        tok_row[t * 2 + threadIdx.x] = r;
    }
    __syncthreads();
    const int c = threadIdx.x * 4;
    f32x4 v = *(const f32x4*)(x + (size_t)t * H_DIM + c);
    u16x4 b;
    b[0] = f2b(v[0]); b[1] = f2b(v[1]); b[2] = f2b(v[2]); b[3] = f2b(v[3]);
    *(u16x4*)&Xg[(size_t)rows[0] * H_DIM + c] = b;
    *(u16x4*)&Xg[(size_t)rows[1] * H_DIM + c] = b;
}

// ================= 8-phase 256-tile K-loop machinery (T2+T3+T4+T5) =============
// LDS tiles: A[256][64], B[256][64] bf16, double-buffered (128KB).
// 16B-chunk XOR swizzle: LDS(row, c) holds global chunk (c ^ (row&7)).
// Staged via glds16 with linear LDS dest + inverse-swizzled global source;
// read with the same swizzle (rule #21).
#define BAR __builtin_amdgcn_s_barrier()
#define LGK0 asm volatile("s_waitcnt lgkmcnt(0)" ::: "memory")
#define VM6 asm volatile("s_waitcnt vmcnt(6)" ::: "memory")
#define VM0 asm volatile("s_waitcnt vmcnt(0)" ::: "memory")
#define VM8 asm volatile("s_waitcnt vmcnt(8)" ::: "memory")

#define STAGE_A01(LA, kk) do { glds16(pA0 + (kk), (LA) + dA0); \
                               glds16(pA1 + (kk), (LA) + dA1); } while (0)
#define STAGE_A23(LA, kk) do { glds16(pA2 + (kk), (LA) + dA2); \
                               glds16(pA3 + (kk), (LA) + dA3); } while (0)
#define STAGE_B4(LB, kk)  do { glds16(pB0 + (kk), (LB) + dB0); \
                               glds16(pB1 + (kk), (LB) + dB1); \
                               glds16(pB2 + (kk), (LB) + dB2); \
                               glds16(pB3 + (kk), (LB) + dB3); } while (0)

#define READ_A(AB, IMB) \
  _Pragma("unroll") \
  for (int im_ = 0; im_ < 4; ++im_) { \
    a[im_][0] = ldfrag((AB) + aoffb + ((IMB) + im_) * 1024 + swz0); \
    a[im_][1] = ldfrag((AB) + aoffb + ((IMB) + im_) * 1024 + swz1); \
  }

#define READ_B2(BB, JNB) \
  _Pragma("unroll") \
  for (int jn_ = 0; jn_ < 2; ++jn_) { \
    b[(JNB) + jn_][0] = ldfrag((BB) + boffb + ((JNB) + jn_) * 1024 + swz0); \
    b[(JNB) + jn_][1] = ldfrag((BB) + boffb + ((JNB) + jn_) * 1024 + swz1); \
  }

#define MFMA16(IMB, JNB) \
  __builtin_amdgcn_s_setprio(1); \
  _Pragma("unroll") \
  for (int im_ = 0; im_ < 4; ++im_) \
    _Pragma("unroll") \
    for (int jn_ = 0; jn_ < 2; ++jn_) { \
      acc[(IMB) + im_][(JNB) + jn_] = __builtin_amdgcn_mfma_f32_16x16x32_bf16( \
          a[im_][0], b[(JNB) + jn_][0], acc[(IMB) + im_][(JNB) + jn_], 0, 0, 0); \
      acc[(IMB) + im_][(JNB) + jn_] = __builtin_amdgcn_mfma_f32_16x16x32_bf16( \
          a[im_][1], b[(JNB) + jn_][1], acc[(IMB) + im_][(JNB) + jn_], 0, 0, 0); \
    } \
  __builtin_amdgcn_s_setprio(0);

// 4 phases over one K-tile. Stage regions are dead by construction:
// A{0-63,128-191} read only in p1 -> staged p2; B fully read by p2 -> staged p3;
// A{64-127,192-255} read only in p3 -> staged p4. Counted vmcnt at p4 only.
#define HALF_TILE(LA, LB, DOSTG, kkn, VMEND) \
  READ_A(LA, 0); READ_B2(LB, 0); \
  BAR; LGK0; MFMA16(0, 0); BAR; \
  READ_B2(LB, 2); if (DOSTG) { STAGE_A01(LA, kkn); } \
  BAR; LGK0; MFMA16(0, 2); BAR; \
  READ_A(LA, 4); if (DOSTG) { STAGE_B4(LB, kkn); } \
  BAR; LGK0; MFMA16(4, 0); BAR; \
  if (DOSTG) { STAGE_A23(LA, kkn); } \
  MFMA16(4, 2); \
  VMEND; BAR;

// ---------------- GEMM1: Hg = silu(Xg @ w1^T) * (Xg @ w3^T) --------------------
// BM=256, BN=128(w1)+128(w3) as one 256-row B tile, BK=64, 8 waves (2M x 4N),
// per-wave 128x64 output. Waves wn<2 hold acc1 (w1), wn>=2 hold acc3 (w3);
// SwiGLU pairing via LDS exchange in the epilogue (reuses the 128KB buffers).
__global__ __launch_bounds__(512) void gemm13_kernel(
    const unsigned short* __restrict__ Xg, const unsigned short* __restrict__ w1b,
    const unsigned short* __restrict__ w3b, const int* __restrict__ offs,
    unsigned short* __restrict__ Hg)
{
    const int e = blockIdx.z;
    const int base = offs[e];
    const int Me = offs[e + 1] - base;
    const int m0 = blockIdx.y * 256;
    if (m0 >= Me) return;
    const int n0 = blockIdx.x * 128;

    const int tid = threadIdx.x;
    const int lane = tid & 63;
    const int wv = tid >> 6;       // 0..7
    const int wm = wv >> 2;        // M half
    const int wn = wv & 3;         // B-row quarter
    const int q = lane >> 4;
    const int frow = lane & 15;
    const int l8 = lane >> 3;
    const int swzS = ((lane & 7) ^ l8) * 8;         // staging source col swizzle
    const int swz0 = (q ^ (frow & 7)) * 8;          // read swizzle, k=0
    const int swz1 = ((4 + q) ^ (frow & 7)) * 8;    // read swizzle, k=1
    const int aoffb = (wm * 128 + frow) * 64;
    const int boffb = (wn * 64 + frow) * 64;

    __shared__ __align__(16) unsigned char SM[131072];
    unsigned short* ldsA0 = (unsigned short*)SM;
    unsigned short* ldsA1 = ldsA0 + 16384;
    unsigned short* ldsB0 = ldsA1 + 16384;
    unsigned short* ldsB1 = ldsB0 + 16384;

    // staging LDS row bases (all multiples of 8)
    const int rA0 = (wv < 4) ? wv * 16 : 128 + (wv - 4) * 16;  // in {0-63,128-191}
    const int rA1 = rA0 + 8, rA2 = rA0 + 64, rA3 = rA0 + 72;   // rA2/3 in {64-127,192-255}
    const int rB0 = wv * 16, rB1 = rB0 + 8;
    const int dA0 = rA0 * 64, dA1 = rA1 * 64, dA2 = rA2 * 64, dA3 = rA3 * 64;
    const int dB0 = rB0 * 64, dB1 = rB1 * 64;
    const int dB2 = (128 + rB0) * 64, dB3 = (128 + rB1) * 64;

    const unsigned short* pAb = Xg + (size_t)(base + m0 + l8) * H_DIM + swzS;
    const unsigned short* pA0 = pAb + (size_t)rA0 * H_DIM;
    const unsigned short* pA1 = pAb + (size_t)rA1 * H_DIM;
    const unsigned short* pA2 = pAb + (size_t)rA2 * H_DIM;
    const unsigned short* pA3 = pAb + (size_t)rA3 * H_DIM;
    const size_t wb = (size_t)e * I_DIM * H_DIM + (size_t)(n0 + l8) * H_DIM + swzS;
    const unsigned short* pB0 = w1b + wb + (size_t)rB0 * H_DIM;  // -> LDS rows rB0
    const unsigned short* pB1 = w1b + wb + (size_t)rB1 * H_DIM;
    const unsigned short* pB2 = w3b + wb + (size_t)rB0 * H_DIM;  // -> LDS rows 128+rB0
    const unsigned short* pB3 = w3b + wb + (size_t)rB1 * H_DIM;

    f32x4 acc[8][4];
#pragma unroll
    for (int i = 0; i < 8; i++)
#pragma unroll
        for (int j = 0; j < 4; j++) acc[i][j] = f32x4{0.f, 0.f, 0.f, 0.f};
    bf16x8 a[4][2], b[4][2];

    // prologue: stage tiles 0 (buf0) and 1 (buf1)
    STAGE_A01(ldsA0, 0); STAGE_A23(ldsA0, 0); STAGE_B4(ldsB0, 0);
    STAGE_A01(ldsA1, 64); STAGE_A23(ldsA1, 64); STAGE_B4(ldsB1, 64);
    VM8; BAR;

    // K = 1024 -> 16 K-tiles, 8 iterations; last peeled (no staging)
#pragma unroll 1
    for (int i = 0; i < 7; ++i) {
        const int kk2 = (2 * i + 2) * 64;
        HALF_TILE(ldsA0, ldsB0, true, kk2, VM6);
        HALF_TILE(ldsA1, ldsB1, true, kk2 + 64, VM6);
    }
    HALF_TILE(ldsA0, ldsB0, false, 0, VM0);
    HALF_TILE(ldsA1, ldsB1, false, 0, (void)0);

    // ---- epilogue: SwiGLU via LDS exchange (scratch = 4 regions x 128x64 f32) ----
    __syncthreads();
    float* sc = (float*)SM;
    const int qs = q & 1;  // bank-spread bit: col' = col ^ (16*qs)
    if (wn >= 2) {
        float* reg = sc + (size_t)((wm << 1) + (wn - 2)) * 8192;
#pragma unroll
        for (int im = 0; im < 8; ++im)
#pragma unroll
            for (int jn = 0; jn < 4; ++jn) {
                float* p = reg + (im * 16 + q * 4) * 64 + ((jn ^ qs) * 16 + frow);
#pragma unroll
                for (int r = 0; r < 4; ++r) p[r * 64] = acc[im][jn][r];
            }
    }
    __syncthreads();
    if (wn < 2) {
        const float* reg = sc + (size_t)((wm << 1) + wn) * 8192;
#pragma unroll
        for (int im = 0; im < 8; ++im) {
#pragma unroll
            for (int jn = 0; jn < 4; ++jn) {
                const float* p = reg + (im * 16 + q * 4) * 64 + ((jn ^ qs) * 16 + frow);
                const int cb = n0 + wn * 64 + jn * 16 + frow;
#pragma unroll
                for (int r = 0; r < 4; ++r) {
                    const int row = m0 + wm * 128 + im * 16 + q * 4 + r;
                    if (row < Me) {
                        float x1 = acc[im][jn][r];
                        float h = (x1 / (1.0f + __expf(-x1))) * p[r * 64];
                        Hg[(size_t)(base + row) * I_DIM + cb] = f2b(h);
                    }
                }
            }
        }
    }
}

// ---------------- GEMM2: Og[row] = Hg[row] @ w2[e]^T (R1 2-phase structure) -----
__global__ __launch_bounds__(256) void gemm2_kernel(
    const unsigned short* __restrict__ Hg, const unsigned short* __restrict__ w2b,
    const int* __restrict__ offs, float* __restrict__ Og)
{
    const int e = blockIdx.z;
    const int base = offs[e];
    const int Me = offs[e + 1] - base;
    const int m0 = blockIdx.y * 128;
    if (m0 >= Me) return;
    const int n0 = blockIdx.x * 128;
    const int tid = threadIdx.x;
    const int lane = tid & 63;
    const int wv = tid >> 6;

    __shared__ __align__(16) unsigned short As[2][128 * BK];
    __shared__ __align__(16) unsigned short Bs[2][128 * BK];

    const int wm = wv & 1;
    const int wn = wv >> 1;
    const int frow = lane & 15;
    const int koff = (lane >> 4) * 8;

    f32x4 acc[4][4];
#pragma unroll
    for (int i = 0; i < 4; i++)
#pragma unroll
        for (int j = 0; j < 4; j++) acc[i][j] = f32x4{0.f, 0.f, 0.f, 0.f};

    const int lrow = lane >> 2;
    const int lcol = (lane & 3) * 8;
    const unsigned short* Ag0 = Hg + (size_t)(base + m0 + wv * 32 + lrow) * I_DIM + lcol;
    const unsigned short* Ag1 = Ag0 + 16 * I_DIM;
    const size_t wbase = (size_t)e * H_DIM * I_DIM;
    const unsigned short* Bg0 = w2b + wbase + (size_t)(n0 + wv * 32 + lrow) * I_DIM + lcol;
    const unsigned short* Bg1 = Bg0 + 16 * I_DIM;
    const int aoff0 = (wv * 2) * 16 * BK;
    const int aoff1 = (wv * 2 + 1) * 16 * BK;

    auto stage = [&](int buf, int kk) {
        glds16(Ag0 + kk, &As[buf][aoff0]);
        glds16(Ag1 + kk, &As[buf][aoff1]);
        glds16(Bg0 + kk, &Bs[buf][aoff0]);
        glds16(Bg1 + kk, &Bs[buf][aoff1]);
    };
    auto comp = [&](const unsigned short* Asb, const unsigned short* Bsb) {
        bf16x8 a[4], b[4];
#pragma unroll
        for (int im = 0; im < 4; im++)
            a[im] = ldfrag(&Asb[(wm * 64 + im * 16 + frow) * BK + koff]);
#pragma unroll
        for (int jn = 0; jn < 4; jn++)
            b[jn] = ldfrag(&Bsb[(wn * 64 + jn * 16 + frow) * BK + koff]);
#pragma unroll
        for (int im = 0; im < 4; im++)
#pragma unroll
            for (int jn = 0; jn < 4; jn++)
                acc[im][jn] = __builtin_amdgcn_mfma_f32_16x16x32_bf16(a[im], b[jn], acc[im][jn], 0, 0, 0);
    };

    stage(0, 0);
    for (int kk = 0; kk < I_DIM; kk += 2 * BK) {
        __syncthreads();
        stage(1, kk + BK);
        comp(As[0], Bs[0]);
        __syncthreads();
        if (kk + 2 * BK < I_DIM) stage(0, kk + 2 * BK);
        comp(As[1], Bs[1]);
    }

#pragma unroll
    for (int im = 0; im < 4; im++) {
        const int rb = m0 + wm * 64 + im * 16 + (lane >> 4) * 4;
#pragma unroll
        for (int jn = 0; jn < 4; jn++) {
            const int cb = n0 + wn * 64 + jn * 16 + frow;
            f32x4 v = acc[im][jn];
#pragma unroll
            for (int r = 0; r < 4; r++) {
                const int row = rb + r;
                if (row < Me)
                    Og[(size_t)(base + row) * H_DIM + cb] = v[r];
            }
        }
    }
}

// ---------------- combine: out[t] = w0*Og[r0] + w1*Og[r1] ----------------
__global__ __launch_bounds__(256) void combine_kernel(
    const float* __restrict__ Og, const int* __restrict__ tok_row,
    const float* __restrict__ tok_w, float* __restrict__ out)
{
    const int t = blockIdx.x;
    const int c = threadIdx.x * 4;
    const int r0 = tok_row[t * 2];
    const int r1 = tok_row[t * 2 + 1];
    const float w0 = tok_w[t * 2];
    const float w1 = tok_w[t * 2 + 1];
    f32x4 a = *(const f32x4*)(Og + (size_t)r0 * H_DIM + c);
    f32x4 b = *(const f32x4*)(Og + (size_t)r1 * H_DIM + c);
    f32x4 o;
#pragma unroll
    for (int i = 0; i < 4; i++) o[i] = a[i] * w0 + b[i] * w1;
    *(f32x4*)(out + (size_t)t * H_DIM + c) = o;
}

extern "C" void kernel_launch(void* const* d_in, const int* in_sizes, int n_in,
                              void* d_out, int out_size, void* d_ws, size_t ws_size,
                              hipStream_t stream) {
    const float* x  = (const float*)d_in[0];
    const float* gw = (const float*)d_in[1];
    const float* gb = (const float*)d_in[2];
    const float* w1 = (const float*)d_in[3];
    const float* w2 = (const float*)d_in[4];
    const float* w3 = (const float*)d_in[5];
    float* out = (float*)d_out;

    char* ws = (char*)d_ws;
    int* counts  = (int*)ws;                 // 8
    int* wptr    = counts + 8;               // 8
    int* offs    = wptr + 8;                 // 9
    int* tok_exp = (int*)(ws + 256);         // 2T
    int* tok_row = tok_exp + 2 * T_DIM;      // 2T
    float* tok_w = (float*)(tok_row + 2 * T_DIM); // 2T
    size_t ofs = 256 + (size_t)3 * 2 * T_DIM * 4;
    ofs = (ofs + 255) & ~(size_t)255;
    const size_t ROWS = 2 * T_DIM + 256;     // slack for 256-tile overshoot
    const long NW = (long)E_DIM * I_DIM * H_DIM;
    unsigned short* Xg  = (unsigned short*)(ws + ofs); ofs += ROWS * H_DIM * 2;
    unsigned short* Hg  = (unsigned short*)(ws + ofs); ofs += ROWS * I_DIM * 2;
    unsigned short* w2b = (unsigned short*)(ws + ofs); ofs += (size_t)NW * 2;
    unsigned short* w1b = (unsigned short*)(ws + ofs); ofs += (size_t)NW * 2;
    unsigned short* w3b = (unsigned short*)(ws + ofs); ofs += (size_t)NW * 2;
    // Og (ROWS*H fp32 = 68MB) aliases w1b+w3b (117MB) — dead after gemm13.
    float* Og = (float*)w1b;

    hipMemsetAsync(counts, 0, 64, stream);
    // zero the tile-overshoot slack rows (NaN-safety for garbage-fed MFMA tails)
    hipMemsetAsync(Xg + (size_t)2 * T_DIM * H_DIM, 0, (size_t)256 * H_DIM * 2, stream);
    hipMemsetAsync(Hg + (size_t)2 * T_DIM * I_DIM, 0, (size_t)256 * I_DIM * 2, stream);
    prep_kernel<<<3 * CONV_BLOCKS + T_DIM / 4, 256, 0, stream>>>(
        w1, w3, w2, w1b, w3b, w2b, x, gw, gb, counts, tok_exp, tok_w);
    scan_kernel<<<1, 64, 0, stream>>>(counts, offs, wptr);
    gather_kernel<<<T_DIM, 256, 0, stream>>>(x, tok_exp, wptr, tok_row, Xg);
    gemm13_kernel<<<dim3(I_DIM / 128, 32, E_DIM), 512, 0, stream>>>(Xg, w1b, w3b, offs, Hg);
    gemm2_kernel<<<dim3(H_DIM / 128, 64, E_DIM), 256, 0, stream>>>(Hg, w2b, offs, Og);
    combine_kernel<<<T_DIM, 256, 0, stream>>>(Og, tok_row, tok_w, out);
}